// Round 2
// baseline (219.715 us; speedup 1.0000x reference)
//
#include <hip/hip_runtime.h>

#define BB 32
#define SS 2048
#define HH 768
#define LL 9
#define NROWS (BB * SS)
#define NCHUNK 64
#define TCHUNK 32  // SS / NCHUNK

// ---------------------------------------------------------------------------
// stable logsumexp over 9 values
__device__ __forceinline__ float lse9(const float* v) {
  float m = fmaxf(fmaxf(fmaxf(fmaxf(v[0], v[1]), fmaxf(v[2], v[3])),
                        fmaxf(fmaxf(v[4], v[5]), fmaxf(v[6], v[7]))),
                  v[8]);
  float s = 0.f;
#pragma unroll
  for (int k = 0; k < 9; ++k) s += __expf(v[k] - m);
  return m + __logf(s);
}

// ---------------------------------------------------------------------------
// Kernel 1: emissions = hs @ W^T + b. Wave-per-row, 8 rows/wave, 2-row
// double-buffered prefetch so 6 dwordx4 loads (6 KB/wave) stay in flight.
__global__ __launch_bounds__(256, 2)
void emis_gemm(const float* __restrict__ hs, const float* __restrict__ W,
               const float* __restrict__ bias, float* __restrict__ em) {
  const int lane = threadIdx.x & 63;
  const int wave = blockIdx.x * 4 + (threadIdx.x >> 6);

  // per-lane W slice: 9 outputs x 12 k-values = 108 VGPRs
  float wreg[LL][12];
#pragma unroll
  for (int l = 0; l < LL; ++l) {
#pragma unroll
    for (int p = 0; p < 3; ++p) {
      float4 t = *reinterpret_cast<const float4*>(W + l * HH + p * 256 + lane * 4);
      wreg[l][p * 4 + 0] = t.x;
      wreg[l][p * 4 + 1] = t.y;
      wreg[l][p * 4 + 2] = t.z;
      wreg[l][p * 4 + 3] = t.w;
    }
  }
  float bl[LL];
#pragma unroll
  for (int l = 0; l < LL; ++l) bl[l] = bias[l];

  const int rowbase = wave * 8;  // grid sized so rowbase+7 < NROWS exactly
  const float4* hp0 = reinterpret_cast<const float4*>(hs + (size_t)rowbase * HH);
  const float4* hp1 = reinterpret_cast<const float4*>(hs + (size_t)(rowbase + 1) * HH);
  float4 c0 = hp0[lane], c1 = hp0[64 + lane], c2 = hp0[128 + lane];
  float4 c3 = hp1[lane], c4 = hp1[64 + lane], c5 = hp1[128 + lane];

#pragma unroll
  for (int p = 0; p < 4; ++p) {
    float4 n0, n1, n2, n3, n4, n5;
    if (p < 3) {  // prefetch next pair while computing current
      const float4* q0 =
          reinterpret_cast<const float4*>(hs + (size_t)(rowbase + 2 * p + 2) * HH);
      const float4* q1 =
          reinterpret_cast<const float4*>(hs + (size_t)(rowbase + 2 * p + 3) * HH);
      n0 = q0[lane]; n1 = q0[64 + lane]; n2 = q0[128 + lane];
      n3 = q1[lane]; n4 = q1[64 + lane]; n5 = q1[128 + lane];
    }
    float h0[12] = {c0.x, c0.y, c0.z, c0.w, c1.x, c1.y,
                    c1.z, c1.w, c2.x, c2.y, c2.z, c2.w};
    float h1[12] = {c3.x, c3.y, c3.z, c3.w, c4.x, c4.y,
                    c4.z, c4.w, c5.x, c5.y, c5.z, c5.w};
    float acc0[LL], acc1[LL];
#pragma unroll
    for (int l = 0; l < LL; ++l) {
      float s0 = 0.f, s1 = 0.f;
#pragma unroll
      for (int q = 0; q < 12; ++q) {
        s0 = fmaf(h0[q], wreg[l][q], s0);
        s1 = fmaf(h1[q], wreg[l][q], s1);
      }
      acc0[l] = s0;
      acc1[l] = s1;
    }
#pragma unroll
    for (int off = 32; off; off >>= 1) {
#pragma unroll
      for (int l = 0; l < LL; ++l) {
        acc0[l] += __shfl_xor(acc0[l], off, 64);
        acc1[l] += __shfl_xor(acc1[l], off, 64);
      }
    }
    if (lane == 0) {
      float* o = em + (size_t)(rowbase + 2 * p) * LL;
#pragma unroll
      for (int l = 0; l < LL; ++l) {
        o[l] = acc0[l] + bl[l];
        o[LL + l] = acc1[l] + bl[l];
      }
    }
    if (p < 3) { c0 = n0; c1 = n1; c2 = n2; c3 = n3; c4 = n4; c5 = n5; }
  }
}

// ---------------------------------------------------------------------------
// Kernel 2: per-chunk transfer matrix + numerator partial (fused).
// Block 128 threads, grid B*NCHUNK. Ping-pong P => 1 barrier/step.
__global__ __launch_bounds__(128)
void crf_chunk(const float* __restrict__ em, const int* __restrict__ lab,
               const float* __restrict__ trans, const float* __restrict__ startT,
               float* __restrict__ Pout, float* __restrict__ numpart,
               int* __restrict__ cntpart) {
  const int blk = blockIdx.x;
  const int b = blk >> 6, c = blk & 63;
  const int tid = threadIdx.x;
  const int lane = tid & 63;
  const int wv = tid >> 6;
  __shared__ float em_s[TCHUNK * LL];  // 288
  __shared__ int lab_s[TCHUNK + 1];    // lab[t0-1 .. t0+31]
  __shared__ float Pbuf[2][81];

  const int t0 = c * TCHUNK;
  const size_t ebase = (size_t)(b * SS + t0) * LL;
  for (int i = tid; i < TCHUNK * LL; i += 128) em_s[i] = em[ebase + i];
  if (tid <= TCHUNK) {
    int g = t0 - 1 + tid;
    lab_s[tid] = (g >= 0) ? lab[b * SS + g] : 0;
  }
  const int i9 = tid / 9, j9 = tid % 9;
  float tc[9];
  if (tid < 81) {
#pragma unroll
    for (int k = 0; k < 9; ++k) tc[k] = trans[k * 9 + j9];
  }
  __syncthreads();

  // both waves compute the identical valid-step bitmask from LDS
  unsigned long long mb =
      __ballot((lane < 32) ? (lab_s[1 + lane] != -100) : false);
  unsigned mask32 = (unsigned)mb;

  // numerator partial: wave 1, lane = local step
  if (wv == 1) {
    float sc = 0.f;
    if (lane < 32) {
      int lv = lab_s[1 + lane];
      int tg = (lv != -100) ? lv : 0;
      if (t0 + lane == 0) {
        sc = startT[tg] + em_s[tg];  // score0, unconditional
      } else if (lv != -100) {
        int pv = lab_s[lane];
        int tp = (pv != -100) ? pv : 0;
        sc = trans[tp * LL + tg] + em_s[lane * LL + tg];
      }
    }
#pragma unroll
    for (int off = 32; off; off >>= 1) sc += __shfl_xor(sc, off, 64);
    if (lane == 0) {
      numpart[blk] = sc;
      cntpart[blk] = __popc(mask32);
    }
  }

  // log-semiring recurrence, threads 0..80
  if (tid < 81) Pbuf[0][tid] = (i9 == j9) ? 0.f : -1e30f;
  __syncthreads();
  int cur = 0;
  const int ltstart = (c == 0) ? 1 : 0;  // t=0 is alpha0, not a matrix
  for (int lt = ltstart; lt < TCHUNK; ++lt) {
    if ((mask32 >> lt) & 1u) {
      if (tid < 81) {
        float v[9];
#pragma unroll
        for (int k = 0; k < 9; ++k) v[k] = Pbuf[cur][i9 * 9 + k] + tc[k];
        Pbuf[cur ^ 1][tid] = lse9(v) + em_s[lt * LL + j9];
      }
      __syncthreads();
      cur ^= 1;
    }
  }
  if (tid < 81) Pout[(size_t)blk * 81 + tid] = Pbuf[cur][tid];
}

// ---------------------------------------------------------------------------
// Kernel 3: per-batch tree fold of 64 chunk matrices (depth 6) + llh.
__global__ __launch_bounds__(128)
void crf_fold(const float* __restrict__ Pm, const float* __restrict__ em,
              const float* __restrict__ startT, const float* __restrict__ endT,
              const float* __restrict__ numpart, const int* __restrict__ cntpart,
              const int* __restrict__ lab, float* __restrict__ llh) {
  const int b = blockIdx.x, tid = threadIdx.x;
  __shared__ float Abuf[64 * 81];  // 20.7 KB
  __shared__ float Bbuf[32 * 81];  // 10.4 KB

  const float* src = Pm + (size_t)b * NCHUNK * 81;
  for (int i = tid; i < 64 * 81; i += 128) Abuf[i] = src[i];
  __syncthreads();

  float* pin = Abuf;
  float* pout = Bbuf;
  for (int n = 32;; n >>= 1) {
    for (int o = tid; o < n * 81; o += 128) {
      int m = o / 81, e = o % 81;
      int i = e / 9, j = e % 9;
      const float* M1 = pin + (2 * m) * 81;
      const float* M2 = pin + (2 * m + 1) * 81;
      float v[9];
#pragma unroll
      for (int k = 0; k < 9; ++k) v[k] = M1[i * 9 + k] + M2[k * 9 + j];
      pout[o] = lse9(v);
    }
    __syncthreads();
    if (n == 1) break;
    float* t = pin; pin = pout;
    pout = (pout == Bbuf) ? Abuf : t;  // ping-pong A<->B
  }
  const float* fin = pout;  // final 9x9 composite

  // numerator totals (wave 0)
  float ns = 0.f;
  int cn = 0;
  if (tid < 64) {
    ns = numpart[b * 64 + tid];
    cn = cntpart[b * 64 + tid];
#pragma unroll
    for (int off = 32; off; off >>= 1) {
      ns += __shfl_xor(ns, off, 64);
      cn += __shfl_xor(cn, off, 64);
    }
  }
  if (tid == 0) {
    float a0[9], af[9], v[9];
#pragma unroll
    for (int j = 0; j < 9; ++j) a0[j] = startT[j] + em[(size_t)b * SS * LL + j];
#pragma unroll
    for (int j = 0; j < 9; ++j) {
#pragma unroll
      for (int k = 0; k < 9; ++k) v[k] = a0[k] + fin[k * 9 + j];
      af[j] = lse9(v);
    }
#pragma unroll
    for (int j = 0; j < 9; ++j) v[j] = af[j] + endT[j];
    float den = lse9(v);
    int se = cn - 1;
    int lt = lab[b * SS + se];
    if (lt == -100) lt = 0;
    llh[b] = (ns + endT[lt]) - den;
  }
}

// ---------------------------------------------------------------------------
// Kernel 4: loss = -mean(llh)
__global__ __launch_bounds__(64)
void finalize(const float* __restrict__ llh, float* __restrict__ out) {
  int l = threadIdx.x;
  float v = (l < BB) ? llh[l] : 0.f;
#pragma unroll
  for (int off = 32; off; off >>= 1) v += __shfl_xor(v, off, 64);
  if (l == 0) out[0] = -v / (float)BB;
}

// ---------------------------------------------------------------------------
extern "C" void kernel_launch(void* const* d_in, const int* in_sizes, int n_in,
                              void* d_out, int out_size, void* d_ws, size_t ws_size,
                              hipStream_t stream) {
  const float* hs = (const float*)d_in[0];      // [B,S,H]
  const float* W = (const float*)d_in[1];       // [L,H]
  const float* bias = (const float*)d_in[2];    // [L]
  const float* startT = (const float*)d_in[3];  // [L]
  const float* endT = (const float*)d_in[4];    // [L]
  const float* trans = (const float*)d_in[5];   // [L,L]
  const int* labels = (const int*)d_in[6];      // [B,S]
  // d_in[7] = attention_mask (unused by the reference)

  float* out = (float*)d_out;  // out[0] = loss, out[1..] = emissions [B,S,L]
  float* em = out + 1;

  float* wsf = (float*)d_ws;
  float* numpart = wsf;                  // [B*NCHUNK]
  int* cntpart = (int*)(wsf + 2048);     // [B*NCHUNK]
  float* Pm = wsf + 4096;                // [B*NCHUNK*81]
  float* llh = wsf + 4096 + 165888;      // [B]

  emis_gemm<<<2048, 256, 0, stream>>>(hs, W, bias, em);
  crf_chunk<<<BB * NCHUNK, 128, 0, stream>>>(em, labels, trans, startT,
                                             Pm, numpart, cntpart);
  crf_fold<<<BB, 128, 0, stream>>>(Pm, em, startT, endT, numpart, cntpart,
                                   labels, llh);
  finalize<<<1, 64, 0, stream>>>(llh, out);
}

// Round 3
// 77.881 us; speedup vs baseline: 2.8212x; 2.8212x over previous
//
#include <hip/hip_runtime.h>

#define BB 32
#define SS 2048
#define HH 768
#define LL 9
#define NROWS (BB * SS)  // 65536
#define NCHUNK 64
#define TCHUNK 32            // SS / NCHUNK
#define PASSES 8             // rows per wave-pair per block
#define ROWS_PER_BLOCK 16    // 2 pairs * PASSES
#define GEMM_BLOCKS (NROWS / ROWS_PER_BLOCK)  // 4096

// ---------------------------------------------------------------------------
// stable logsumexp over 9 values
__device__ __forceinline__ float lse9(const float* v) {
  float m = fmaxf(fmaxf(fmaxf(fmaxf(v[0], v[1]), fmaxf(v[2], v[3])),
                        fmaxf(fmaxf(v[4], v[5]), fmaxf(v[6], v[7]))),
                  v[8]);
  float s = 0.f;
#pragma unroll
  for (int k = 0; k < 9; ++k) s += __expf(v[k] - m);
  return m + __logf(s);
}

// ---------------------------------------------------------------------------
// DPP add: VALU-pipe cross-lane (no DS ops). CTRL is an ICE via template.
template <int CTRL>
__device__ __forceinline__ float dpp_add(float x) {
  int t = __builtin_amdgcn_update_dpp(0, __float_as_int(x), CTRL, 0xf, 0xf, true);
  return x + __int_as_float(t);
}
// sum over each 16-lane row; xor-masks {1,2,7,15} span GF(2)^4 -> every lane
// of the 16-group ends with the full group sum.
__device__ __forceinline__ float red16(float x) {
  x = dpp_add<0xB1>(x);   // quad_perm [1,0,3,2] : xor 1
  x = dpp_add<0x4E>(x);   // quad_perm [2,3,0,1] : xor 2
  x = dpp_add<0x141>(x);  // row_half_mirror     : xor 7
  x = dpp_add<0x140>(x);  // row_mirror          : xor 15
  return x;
}

// ---------------------------------------------------------------------------
// Kernel 1: emissions = hs @ W^T + b.
// Wave pair per row (each wave: 384 k-values, 6 per lane -> wr = 54 VGPRs).
// DPP 16-lane reduce -> 4 partials/wave -> LDS; one barrier per block;
// combine phase sums 8 partials per row. 2-deep row prefetch, never drained
// by a barrier inside the pass loop.
__global__ __launch_bounds__(256)
void emis_gemm(const float* __restrict__ hs, const float* __restrict__ W,
               const float* __restrict__ bias, float* __restrict__ em) {
  const int tid = threadIdx.x;
  const int lane = tid & 63;
  const int w = tid >> 6;   // wave 0..3
  const int pair = w >> 1;  // 0,1 : which row stream
  const int half = w & 1;   // 0,1 : which k-half
  const int rowbase = blockIdx.x * ROWS_PER_BLOCK;
  const int kb = half * 384;

  __shared__ float part[ROWS_PER_BLOCK][8][LL];  // 4608 B

  // W slice: 9 labels x 6 k-values = 54 VGPRs (from L2/L3, reused chip-wide)
  float wr[LL][6];
#pragma unroll
  for (int l = 0; l < LL; ++l) {
    float4 t4 = *reinterpret_cast<const float4*>(W + l * HH + kb + lane * 4);
    float2 t2 = *reinterpret_cast<const float2*>(W + l * HH + kb + 256 + lane * 2);
    wr[l][0] = t4.x; wr[l][1] = t4.y; wr[l][2] = t4.z; wr[l][3] = t4.w;
    wr[l][4] = t2.x; wr[l][5] = t2.y;
  }

  // prefetch rows for pass 0 and 1
  const float* r0 = hs + (size_t)(rowbase + 0 * 2 + pair) * HH + kb;
  float4 a4 = *reinterpret_cast<const float4*>(r0 + lane * 4);
  float2 a2 = *reinterpret_cast<const float2*>(r0 + 256 + lane * 2);
  const float* r1 = hs + (size_t)(rowbase + 1 * 2 + pair) * HH + kb;
  float4 b4 = *reinterpret_cast<const float4*>(r1 + lane * 4);
  float2 b2 = *reinterpret_cast<const float2*>(r1 + 256 + lane * 2);

#pragma unroll
  for (int p = 0; p < PASSES; ++p) {
    float4 c4{};
    float2 c2{};
    if (p + 2 < PASSES) {  // static under full unroll
      const float* rn = hs + (size_t)(rowbase + (p + 2) * 2 + pair) * HH + kb;
      c4 = *reinterpret_cast<const float4*>(rn + lane * 4);
      c2 = *reinterpret_cast<const float2*>(rn + 256 + lane * 2);
    }
    const float h[6] = {a4.x, a4.y, a4.z, a4.w, a2.x, a2.y};
    if ((lane & 15) == 0) {
      // placeholder to keep part-index regs alive cheaply (no-op)
    }
    float acc[LL];
#pragma unroll
    for (int l = 0; l < LL; ++l) {
      float s = h[0] * wr[l][0];
#pragma unroll
      for (int q = 1; q < 6; ++q) s = fmaf(h[q], wr[l][q], s);
      acc[l] = red16(s);
    }
    if ((lane & 15) == 0) {
      const int pi = half * 4 + (lane >> 4);  // which 16-lane group
      const int o = p * 2 + pair;
#pragma unroll
      for (int l = 0; l < LL; ++l) part[o][pi][l] = acc[l];
    }
    a4 = b4; a2 = b2; b4 = c4; b2 = c2;
  }
  __syncthreads();

  // combine 8 partials per row + bias, coalesced stores (tid < 144)
  for (int j = tid; j < ROWS_PER_BLOCK * LL; j += 256) {
    const int o = j / LL, l = j - o * LL;
    float s = bias[l];
#pragma unroll
    for (int q = 0; q < 8; ++q) s += part[o][q][l];
    em[(size_t)(rowbase + o) * LL + l] = s;
  }
}

// ---------------------------------------------------------------------------
// Kernel 2: per-chunk transfer matrix + numerator partial (fused).
__global__ __launch_bounds__(128)
void crf_chunk(const float* __restrict__ em, const int* __restrict__ lab,
               const float* __restrict__ trans, const float* __restrict__ startT,
               float* __restrict__ Pout, float* __restrict__ numpart,
               int* __restrict__ cntpart) {
  const int blk = blockIdx.x;
  const int b = blk >> 6, c = blk & 63;
  const int tid = threadIdx.x;
  const int lane = tid & 63;
  const int wv = tid >> 6;
  __shared__ float em_s[TCHUNK * LL];
  __shared__ int lab_s[TCHUNK + 1];
  __shared__ float Pbuf[2][81];

  const int t0 = c * TCHUNK;
  const size_t ebase = (size_t)(b * SS + t0) * LL;
  for (int i = tid; i < TCHUNK * LL; i += 128) em_s[i] = em[ebase + i];
  if (tid <= TCHUNK) {
    int g = t0 - 1 + tid;
    lab_s[tid] = (g >= 0) ? lab[b * SS + g] : 0;
  }
  const int i9 = tid / 9, j9 = tid % 9;
  float tc[9];
  if (tid < 81) {
#pragma unroll
    for (int k = 0; k < 9; ++k) tc[k] = trans[k * 9 + j9];
  }
  __syncthreads();

  unsigned long long mb =
      __ballot((lane < 32) ? (lab_s[1 + lane] != -100) : false);
  unsigned mask32 = (unsigned)mb;

  if (wv == 1) {
    float sc = 0.f;
    if (lane < 32) {
      int lv = lab_s[1 + lane];
      int tg = (lv != -100) ? lv : 0;
      if (t0 + lane == 0) {
        sc = startT[tg] + em_s[tg];
      } else if (lv != -100) {
        int pv = lab_s[lane];
        int tp = (pv != -100) ? pv : 0;
        sc = trans[tp * LL + tg] + em_s[lane * LL + tg];
      }
    }
#pragma unroll
    for (int off = 32; off; off >>= 1) sc += __shfl_xor(sc, off, 64);
    if (lane == 0) {
      numpart[blk] = sc;
      cntpart[blk] = __popc(mask32);
    }
  }

  if (tid < 81) Pbuf[0][tid] = (i9 == j9) ? 0.f : -1e30f;
  __syncthreads();
  int cur = 0;
  const int ltstart = (c == 0) ? 1 : 0;
  for (int lt = ltstart; lt < TCHUNK; ++lt) {
    if ((mask32 >> lt) & 1u) {
      if (tid < 81) {
        float v[9];
#pragma unroll
        for (int k = 0; k < 9; ++k) v[k] = Pbuf[cur][i9 * 9 + k] + tc[k];
        Pbuf[cur ^ 1][tid] = lse9(v) + em_s[lt * LL + j9];
      }
      __syncthreads();
      cur ^= 1;
    }
  }
  if (tid < 81) Pout[(size_t)blk * 81 + tid] = Pbuf[cur][tid];
}

// ---------------------------------------------------------------------------
// Kernel 3: per-batch tree fold of 64 chunk matrices (depth 6) + llh.
__global__ __launch_bounds__(128)
void crf_fold(const float* __restrict__ Pm, const float* __restrict__ em,
              const float* __restrict__ startT, const float* __restrict__ endT,
              const float* __restrict__ numpart, const int* __restrict__ cntpart,
              const int* __restrict__ lab, float* __restrict__ llh) {
  const int b = blockIdx.x, tid = threadIdx.x;
  __shared__ float Abuf[64 * 81];
  __shared__ float Bbuf[32 * 81];

  const float* src = Pm + (size_t)b * NCHUNK * 81;
  for (int i = tid; i < 64 * 81; i += 128) Abuf[i] = src[i];
  __syncthreads();

  float* pin = Abuf;
  float* pout = Bbuf;
  for (int n = 32;; n >>= 1) {
    for (int o = tid; o < n * 81; o += 128) {
      int m = o / 81, e = o % 81;
      int i = e / 9, j = e % 9;
      const float* M1 = pin + (2 * m) * 81;
      const float* M2 = pin + (2 * m + 1) * 81;
      float v[9];
#pragma unroll
      for (int k = 0; k < 9; ++k) v[k] = M1[i * 9 + k] + M2[k * 9 + j];
      pout[o] = lse9(v);
    }
    __syncthreads();
    if (n == 1) break;
    float* t = pin; pin = pout;
    pout = (pout == Bbuf) ? Abuf : t;
  }
  const float* fin = pout;

  float ns = 0.f;
  int cn = 0;
  if (tid < 64) {
    ns = numpart[b * 64 + tid];
    cn = cntpart[b * 64 + tid];
#pragma unroll
    for (int off = 32; off; off >>= 1) {
      ns += __shfl_xor(ns, off, 64);
      cn += __shfl_xor(cn, off, 64);
    }
  }
  if (tid == 0) {
    float a0[9], af[9], v[9];
#pragma unroll
    for (int j = 0; j < 9; ++j) a0[j] = startT[j] + em[(size_t)b * SS * LL + j];
#pragma unroll
    for (int j = 0; j < 9; ++j) {
#pragma unroll
      for (int k = 0; k < 9; ++k) v[k] = a0[k] + fin[k * 9 + j];
      af[j] = lse9(v);
    }
#pragma unroll
    for (int j = 0; j < 9; ++j) v[j] = af[j] + endT[j];
    float den = lse9(v);
    int se = cn - 1;
    int lt = lab[b * SS + se];
    if (lt == -100) lt = 0;
    llh[b] = (ns + endT[lt]) - den;
  }
}

// ---------------------------------------------------------------------------
// Kernel 4: loss = -mean(llh)
__global__ __launch_bounds__(64)
void finalize(const float* __restrict__ llh, float* __restrict__ out) {
  int l = threadIdx.x;
  float v = (l < BB) ? llh[l] : 0.f;
#pragma unroll
  for (int off = 32; off; off >>= 1) v += __shfl_xor(v, off, 64);
  if (l == 0) out[0] = -v / (float)BB;
}

// ---------------------------------------------------------------------------
extern "C" void kernel_launch(void* const* d_in, const int* in_sizes, int n_in,
                              void* d_out, int out_size, void* d_ws, size_t ws_size,
                              hipStream_t stream) {
  const float* hs = (const float*)d_in[0];
  const float* W = (const float*)d_in[1];
  const float* bias = (const float*)d_in[2];
  const float* startT = (const float*)d_in[3];
  const float* endT = (const float*)d_in[4];
  const float* trans = (const float*)d_in[5];
  const int* labels = (const int*)d_in[6];

  float* out = (float*)d_out;  // out[0] = loss, out[1..] = emissions [B,S,L]
  float* em = out + 1;

  float* wsf = (float*)d_ws;
  float* numpart = wsf;               // [B*NCHUNK]
  int* cntpart = (int*)(wsf + 2048);  // [B*NCHUNK]
  float* Pm = wsf + 4096;             // [B*NCHUNK*81]
  float* llh = wsf + 4096 + 165888;   // [B]

  emis_gemm<<<GEMM_BLOCKS, 256, 0, stream>>>(hs, W, bias, em);
  crf_chunk<<<BB * NCHUNK, 128, 0, stream>>>(em, labels, trans, startT,
                                             Pm, numpart, cntpart);
  crf_fold<<<BB, 128, 0, stream>>>(Pm, em, startT, endT, numpart, cntpart,
                                   labels, llh);
  finalize<<<1, 64, 0, stream>>>(llh, out);
}